// Round 4
// baseline (150.719 us; speedup 1.0000x reference)
//
#include <hip/hip_runtime.h>
#include <hip/hip_bf16.h>
#include <stdint.h>

typedef unsigned short u16;
typedef __attribute__((ext_vector_type(8))) short short8;
typedef __attribute__((ext_vector_type(4))) float f32x4;

// ---------- helpers ----------
__device__ __forceinline__ u16 f2bf(float f) {
    union { float f; uint32_t u; } c; c.f = f;
    uint32_t u = c.u;
    u += 0x7fffu + ((u >> 16) & 1u);   // round-to-nearest-even
    return (u16)(u >> 16);
}

__device__ __forceinline__ void glds16(const void* g, void* l) {
    __builtin_amdgcn_global_load_lds(
        (const __attribute__((address_space(1))) uint32_t*)g,
        (__attribute__((address_space(3))) uint32_t*)l,
        16, 0, 0);
}

// ---------- kernel 1: g_p = FWHT_1024(D_p[:1024] * V) / 1024, for 4 params ----------
__global__ void fwht_g_kernel(const float* __restrict__ V,
                              const float* __restrict__ D0, const float* __restrict__ D1,
                              const float* __restrict__ D2, const float* __restrict__ D3,
                              float* __restrict__ g) {
    __shared__ float s[1024];
    int t = threadIdx.x;
    const float* D = (blockIdx.x == 0) ? D0 : (blockIdx.x == 1) ? D1 :
                     (blockIdx.x == 2) ? D2 : D3;
    s[t] = D[t] * V[t];
    __syncthreads();
    #pragma unroll
    for (int st = 512; st >= 1; st >>= 1) {
        float a = s[t];
        float b = s[t ^ st];
        __syncthreads();
        s[t] = (t & st) ? (b - a) : (a + b);
        __syncthreads();
    }
    g[blockIdx.x * 1024 + t] = s[t] * (1.0f / 1024.0f);
}

// ---------- kernel 2: bias = init + PP * g[i&1023] ----------
__global__ void bias_kernel(const float* __restrict__ init, const float* __restrict__ PP,
                            const float* __restrict__ g, float* __restrict__ out, int n) {
    int i = blockIdx.x * blockDim.x + threadIdx.x;
    if (i < n) out[i] = init[i] + PP[i] * g[i & 1023];
}

// ---------- kernel 3: f32 -> bf16 cast (x), 4 elems/thread ----------
__global__ void cast_kernel(const float* __restrict__ in, u16* __restrict__ out, int n4) {
    int i = blockIdx.x * blockDim.x + threadIdx.x;
    if (i >= n4) return;
    float4 v = ((const float4*)in)[i];
    uint32_t lo = (uint32_t)f2bf(v.x) | ((uint32_t)f2bf(v.y) << 16);
    uint32_t hi = (uint32_t)f2bf(v.z) | ((uint32_t)f2bf(v.w) << 16);
    ((uint2*)out)[i] = make_uint2(lo, hi);
}

// ---------- kernel 4: fused W-gen + split-K GEMM ----------
// P[sk] += A(512xKs bf16) @ W^T where W[n][k] = bf16(Winit + PP * g[k&1023]) generated
// on the fly into LDS. BM=512 (full M) so W inputs are read from HBM exactly once.
// BN=32, BK=64, S=4. 512 threads = 8 waves stacked in M; wave tile 64x32, acc[4][2].
__global__ __launch_bounds__(512, 4) void gemm_fused(const u16* __restrict__ A,
                                                     const float* __restrict__ Winit,
                                                     const float* __restrict__ PP,
                                                     const float* __restrict__ gvec,
                                                     float* __restrict__ P,
                                                     int M, int N, int K, int Kslice) {
    constexpr int BM = 512, BN = 32, BK = 64;
    __shared__ u16 As[BM * BK];   // 64 KB
    __shared__ u16 Bs[BN * BK];   // 4 KB

    const int t    = threadIdx.x;
    const int wid  = t >> 6;          // 0..7, wave row block (64 rows each)
    const int lane = t & 63;
    const int fr   = lane & 15;
    const int fq   = lane >> 4;

    const int bn = blockIdx.x, sk = blockIdx.y;
    const int k_beg = sk * Kslice;

    // B-gen thread mapping: 32 rows x 64 k = 2048 elems, 4 per thread (one float4 in k)
    const int rowB = t >> 4;          // 0..31
    const int kkB  = (t & 15) * 4;    // 0..60
    const float* Wrow = Winit + (size_t)(bn * BN + rowB) * K;
    const float* Prow = PP    + (size_t)(bn * BN + rowB) * K;

    f32x4 acc[4][2];
    #pragma unroll
    for (int m = 0; m < 4; ++m)
        #pragma unroll
        for (int n = 0; n < 2; ++n)
            acc[m][n] = (f32x4){0.f, 0.f, 0.f, 0.f};

    for (int k0 = k_beg; k0 < k_beg + Kslice; k0 += BK) {
        // stage A: 512x64 bf16 = 64 KB = 8 rounds x 512 thr x 16 B (direct to LDS)
        #pragma unroll
        for (int q = 0; q < 8; ++q) {
            int L = q * 512 + t;
            int row = L >> 3;
            int cg  = (L & 7) * 8;
            glds16(A + (size_t)row * K + k0 + cg, As + L * 8);
        }
        // generate B tile: bf16(Winit + PP * g[k & 1023])
        {
            float4 wi = *(const float4*)(Wrow + k0 + kkB);
            float4 pp = *(const float4*)(Prow + k0 + kkB);
            float4 gv = *(const float4*)(gvec + ((k0 + kkB) & 1023));
            uint32_t lo = (uint32_t)f2bf(wi.x + pp.x * gv.x) | ((uint32_t)f2bf(wi.y + pp.y * gv.y) << 16);
            uint32_t hi = (uint32_t)f2bf(wi.z + pp.z * gv.z) | ((uint32_t)f2bf(wi.w + pp.w * gv.w) << 16);
            *(uint2*)(Bs + rowB * BK + kkB) = make_uint2(lo, hi);
        }
        __syncthreads();   // drains vmcnt (glds) + lgkmcnt (ds_write)

        #pragma unroll
        for (int ks = 0; ks < 2; ++ks) {
            short8 a[4], b[2];
            #pragma unroll
            for (int m = 0; m < 4; ++m)
                a[m] = *(const short8*)(As + (wid * 64 + m * 16 + fr) * BK + ks * 32 + fq * 8);
            #pragma unroll
            for (int n = 0; n < 2; ++n)
                b[n] = *(const short8*)(Bs + (n * 16 + fr) * BK + ks * 32 + fq * 8);
            #pragma unroll
            for (int m = 0; m < 4; ++m)
                #pragma unroll
                for (int n = 0; n < 2; ++n)
                    acc[m][n] = __builtin_amdgcn_mfma_f32_16x16x32_bf16(a[m], b[n], acc[m][n], 0, 0, 0);
        }
        __syncthreads();
    }

    // epilogue: write f32 partial tile
    float* Pp = P + (size_t)sk * M * N;
    #pragma unroll
    for (int m = 0; m < 4; ++m) {
        int grow0 = wid * 64 + m * 16 + fq * 4;
        #pragma unroll
        for (int n = 0; n < 2; ++n) {
            int gcol = bn * BN + n * 16 + fr;
            #pragma unroll
            for (int j = 0; j < 4; ++j)
                Pp[(size_t)(grow0 + j) * N + gcol] = acc[m][n][j];
        }
    }
}

// ---------- kernel 5: reduce S partials + bias (+relu) -> bf16 or f32 ----------
template <typename OutT, bool RELU, int S>
__global__ void reduce_kernel(const float* __restrict__ P, const float* __restrict__ bias,
                              OutT* __restrict__ out, int MN, int N) {
    int i = blockIdx.x * blockDim.x + threadIdx.x;   // handles 4 elems
    if (i * 4 >= MN) return;
    int e = i * 4;
    int col = e & (N - 1);
    float4 acc = ((const float4*)(P + e))[0];
    #pragma unroll
    for (int s = 1; s < S; ++s) {
        float4 p = ((const float4*)(P + (size_t)s * MN + e))[0];
        acc.x += p.x; acc.y += p.y; acc.z += p.z; acc.w += p.w;
    }
    float4 bv = *((const float4*)(bias + col));
    acc.x += bv.x; acc.y += bv.y; acc.z += bv.z; acc.w += bv.w;
    if (RELU) {
        acc.x = fmaxf(acc.x, 0.f); acc.y = fmaxf(acc.y, 0.f);
        acc.z = fmaxf(acc.z, 0.f); acc.w = fmaxf(acc.w, 0.f);
    }
    if constexpr (sizeof(OutT) == 2) {
        uint32_t lo = (uint32_t)f2bf(acc.x) | ((uint32_t)f2bf(acc.y) << 16);
        uint32_t hi = (uint32_t)f2bf(acc.z) | ((uint32_t)f2bf(acc.w) << 16);
        ((uint2*)out)[i] = make_uint2(lo, hi);
    } else {
        ((float4*)out)[i] = acc;
    }
}

// ---------- launch ----------
extern "C" void kernel_launch(void* const* d_in, const int* in_sizes, int n_in,
                              void* d_out, int out_size, void* d_ws, size_t ws_size,
                              hipStream_t stream) {
    (void)in_sizes; (void)n_in; (void)out_size; (void)ws_size;

    const float* x       = (const float*)d_in[0];
    const float* V       = (const float*)d_in[1];
    const float* W1_init = (const float*)d_in[2];
    const float* D_W1    = (const float*)d_in[3];
    const float* PP_W1   = (const float*)d_in[4];
    const float* b1_init = (const float*)d_in[5];
    const float* D_b1    = (const float*)d_in[6];
    const float* PP_b1   = (const float*)d_in[7];
    const float* W2_init = (const float*)d_in[8];
    const float* D_W2    = (const float*)d_in[9];
    const float* PP_W2   = (const float*)d_in[10];
    const float* b2_init = (const float*)d_in[11];
    const float* D_b2    = (const float*)d_in[12];
    const float* PP_b2   = (const float*)d_in[13];

    constexpr size_t MB = 1024 * 1024;
    char* ws = (char*)d_ws;
    float* g    = (float*)(ws);                      // 4x1024 f32: [W1 | b1 | W2 | b2]
    float* b1w  = (float*)(ws + 16384);              // 4096 f32
    float* b2w  = (float*)(ws + 32768);              // 4096 f32
    u16*   xb   = (u16*)(ws + 65536);                // 512x4096 bf16 (4 MB)
    u16*   hb   = (u16*)(ws + 65536 + 4 * MB);       // 512x4096 bf16 (4 MB)
    float* Pbuf = (float*)(ws + 65536 + 8 * MB);     // 4x512x4096 f32 (32 MB)

    const int M = 512, N = 4096, K = 4096, S = 4, Kslice = K / S;

    fwht_g_kernel<<<4, 1024, 0, stream>>>(V, D_W1, D_b1, D_W2, D_b2, g);
    bias_kernel<<<4, 1024, 0, stream>>>(b1_init, PP_b1, g + 1024, b1w, 4096);
    bias_kernel<<<4, 1024, 0, stream>>>(b2_init, PP_b2, g + 3072, b2w, 4096);
    cast_kernel<<<2048, 256, 0, stream>>>(x, xb, M * K / 4);

    // layer 1: fused W1-gen GEMM
    gemm_fused<<<dim3(N / 32, S), 512, 0, stream>>>(xb, W1_init, PP_W1, g, Pbuf, M, N, K, Kslice);
    reduce_kernel<u16, true, S><<<M * N / 4 / 256, 256, 0, stream>>>(Pbuf, b1w, hb, M * N, N);

    // layer 2: fused W2-gen GEMM
    gemm_fused<<<dim3(N / 32, S), 512, 0, stream>>>(hb, W2_init, PP_W2, g + 2048, Pbuf, M, N, K, Kslice);
    reduce_kernel<float, false, S><<<M * N / 4 / 256, 256, 0, stream>>>(Pbuf, b2w, (float*)d_out, M * N, N);
}